// Round 9
// baseline (172.384 us; speedup 1.0000x reference)
//
#include <hip/hip_runtime.h>
#include <hip/hip_fp16.h>

#define BB 16
#define NN 512
#define DD 64
#define ROWS (BB * NN)   // 8192
#define RB 32            // rows per k1 block
#define JCH 64           // j-chunks per sample in k2
#define CHUNK (NN / JCH) // 8 sources per chunk
#define PROBE_REPS 6

typedef _Float16 v8h __attribute__((ext_vector_type(8)));
typedef float    v4f __attribute__((ext_vector_type(4)));

static __device__ __forceinline__ __half2 h2bits(unsigned int u) {
    union { unsigned int i; __half2 h; } c; c.i = u; return c.h;
}
static __device__ __forceinline__ unsigned int bits2(__half2 h) {
    union { __half2 h; unsigned int i; } c; c.h = h; return c.i;
}
// acc += sign2 * |u2 + v2|   (v_pk_add_f16, v_and_b32, v_pk_fma_f16)
static __device__ __forceinline__ __half2 absterm(unsigned int s, unsigned int u,
                                                  unsigned int v, __half2 a) {
    return __hfma2(h2bits(s), __habs2(__hadd2(h2bits(u), h2bits(v))), a);
}
static __device__ __forceinline__ v8h load_cvt8(const float* __restrict__ p) {
    const float4 a = *reinterpret_cast<const float4*>(p);
    const float4 b = *reinterpret_cast<const float4*>(p + 4);
    v8h r;
    r[0] = (_Float16)a.x; r[1] = (_Float16)a.y; r[2] = (_Float16)a.z; r[3] = (_Float16)a.w;
    r[4] = (_Float16)b.x; r[5] = (_Float16)b.y; r[6] = (_Float16)b.z; r[7] = (_Float16)b.w;
    return r;
}

// ---------------- Kernel 1: node transforms via MFMA (R8, unchanged) ----------
__global__ __launch_bounds__(256, 2) void k1_transform(
    const float* __restrict__ x,
    const float* __restrict__ Wl, const float* __restrict__ bl,
    const float* __restrict__ Wr, const float* __restrict__ br,
    const float* __restrict__ att, const float* __restrict__ bias,
    const float* __restrict__ Wf, const float* __restrict__ bf,
    unsigned int* __restrict__ uh, unsigned int* __restrict__ vh,
    float2* __restrict__ epj,
    unsigned int* __restrict__ sgnh, float* __restrict__ cterm)
{
    __shared__ float xacc[RB][132];
    __shared__ float red[RB][16][2];

    const int tid = threadIdx.x;
    const int r0 = blockIdx.x * RB;

    {
        const int w    = tid >> 6;
        const int lane = tid & 63;
        const int rowhalf = w >> 1;
        const int colhalf = w & 1;
        const int kb = (lane >> 4) * 8;

        const int arow = r0 + rowhalf * 16 + (lane & 15);
        const v8h A0 = load_cvt8(&x[(size_t)arow * DD + 0  + kb]);
        const v8h A1 = load_cvt8(&x[(size_t)arow * DD + 32 + kb]);

        v4f acc[4];
        #pragma unroll
        for (int t = 0; t < 4; ++t) acc[t] = (v4f){0.f, 0.f, 0.f, 0.f};

        #pragma unroll
        for (int t = 0; t < 4; ++t) {
            const int c = colhalf * 64 + t * 16 + (lane & 15);
            const float* wrow = (c < 64) ? (Wl + (size_t)c * DD)
                                         : (Wr + (size_t)(c - 64) * DD);
            const v8h B0 = load_cvt8(wrow + 0  + kb);
            const v8h B1 = load_cvt8(wrow + 32 + kb);
            acc[t] = __builtin_amdgcn_mfma_f32_16x16x32_f16(A0, B0, acc[t], 0, 0, 0);
            acc[t] = __builtin_amdgcn_mfma_f32_16x16x32_f16(A1, B1, acc[t], 0, 0, 0);
        }

        const int rbase = rowhalf * 16 + (lane >> 4) * 4;
        #pragma unroll
        for (int t = 0; t < 4; ++t) {
            const int col = colhalf * 64 + t * 16 + (lane & 15);
            #pragma unroll
            for (int r = 0; r < 4; ++r)
                xacc[rbase + r][col] = acc[t][r];
        }
    }
    __syncthreads();

    {
        const int g  = tid & 31;
        const int rq = tid >> 5;
        const int c0 = g * 4;
        const int ra = rq * 4;
        const bool isL = (c0 < 64);
        const int d0 = c0 & 63;

        const float4 bv = *reinterpret_cast<const float4*>((isL ? bl : br) + d0);
        const float4 av = *reinterpret_cast<const float4*>(&att[d0]);
        const float4 wfv = *reinterpret_cast<const float4*>(&Wf[d0]);

        unsigned int* const dst = isL ? vh : uh;
        const int q    = d0 >> 3;
        const int slot = (d0 & 4) ? 2 : 0;
        const int base = ((r0 >> 9) * 8 + q) * 512 + (r0 & 511);

        #pragma unroll
        for (int r = 0; r < 4; ++r) {
            float4 val = *reinterpret_cast<const float4*>(&xacc[ra + r][c0]);
            val.x += bv.x; val.y += bv.y; val.z += bv.z; val.w += bv.w;

            if (isL) {
                red[ra + r][g][0] = av.x * val.x + av.y * val.y + av.z * val.z + av.w * val.w;
                red[ra + r][g][1] = wfv.x * val.x + wfv.y * val.y + wfv.z * val.z + wfv.w * val.w;
            }
            uint2 pk;
            pk.x = bits2(__floats2half2_rn(0.4f * av.x * val.x, 0.4f * av.y * val.y));
            pk.y = bits2(__floats2half2_rn(0.4f * av.z * val.z, 0.4f * av.w * val.w));
            *reinterpret_cast<uint2*>(&dst[(size_t)(base + ra + r) * 4 + slot]) = pk;
        }
    }
    __syncthreads();

    if (tid < RB) {
        float a = 0.f, p = 0.f;
        #pragma unroll
        for (int gg = 0; gg < 16; ++gg) {
            a += red[tid][gg][0];
            p += red[tid][gg][1];
        }
        const float E = __expf(0.6f * a);
        epj[r0 + tid] = make_float2(E, E * p);
    }

    if (blockIdx.x == 0) {
        if (tid < 32) {
            const float s0 = (att[2 * tid]     >= 0.f) ? 1.f : -1.f;
            const float s1 = (att[2 * tid + 1] >= 0.f) ? 1.f : -1.f;
            sgnh[tid] = bits2(__floats2half2_rn(s0, s1));
        }
        if (tid == 0) {
            float ct = bf[0];
            #pragma unroll 8
            for (int d = 0; d < DD; ++d) ct = fmaf(bias[d], Wf[d], ct);
            *cterm = ct;
        }
    }
}

// ---------------- k2 core body (shared by real kernel and probe) ----------------
static __device__ __forceinline__ void k2_body(
    const unsigned int* __restrict__ vh, const float2* __restrict__ epj,
    const uint4* uu, const unsigned int* sgv, int b, int j0,
    float& s_out, float& sp_out)
{
    float s = 0.f, sp = 0.f;
    #pragma unroll 2
    for (int jj = 0; jj < CHUNK; ++jj) {
        const int j = j0 + jj;
        __half2 a0 = __float2half2_rn(0.f), a1 = a0;
        #pragma unroll
        for (int q = 0; q < 8; ++q) {
            const uint4 vq = *reinterpret_cast<const uint4*>(
                &vh[(size_t)(((b * 8 + q) << 9) + j) * 4]);   // wave-uniform
            a0 = absterm(sgv[q * 4 + 0], uu[q].x, vq.x, a0);
            a1 = absterm(sgv[q * 4 + 1], uu[q].y, vq.y, a1);
            a0 = absterm(sgv[q * 4 + 2], uu[q].z, vq.z, a0);
            a1 = absterm(sgv[q * 4 + 3], uu[q].w, vq.w, a1);
        }
        const __half2 h = __hadd2(a0, a1);
        const float f = __low2float(h) + __high2float(h);
        const float t = __expf(f);
        const float2 ep = epj[(b << 9) + j];                   // wave-uniform
        s  = fmaf(t, ep.x, s);
        sp = fmaf(t, ep.y, sp);
    }
    s_out = s;
    sp_out = sp;
}

// ---------------- Kernel 2: streaming scores; VGPR<=64, 32 waves/CU ----------
__global__ __launch_bounds__(512, 8) void k2_attn(
    const unsigned int* __restrict__ uh, const unsigned int* __restrict__ vh,
    const float2* __restrict__ epj, const unsigned int* __restrict__ sgnh,
    float2* __restrict__ part)
{
    const int b  = blockIdx.x >> 6;
    const int jc = blockIdx.x & 63;
    const int i  = threadIdx.x;

    uint4 uu[8];
    #pragma unroll
    for (int q = 0; q < 8; ++q)
        uu[q] = *reinterpret_cast<const uint4*>(&uh[(size_t)(((b * 8 + q) << 9) + i) * 4]);

    unsigned int sgv[32];     // force SGPR residency
    #pragma unroll
    for (int c = 0; c < 32; ++c)
        sgv[c] = __builtin_amdgcn_readfirstlane(sgnh[c]);

    float s, sp;
    k2_body(vh, epj, uu, sgv, b, jc * CHUNK, s, sp);
    part[(size_t)(((b << 6) + jc) << 9) + i] = make_float2(s, sp);
}

// ---------------- Probe: same body x PROBE_REPS, surfaces in top-5 ----------
__global__ __launch_bounds__(512, 8) void k2_probe(
    const unsigned int* __restrict__ uh, const unsigned int* __restrict__ vh,
    const float2* __restrict__ epj, const unsigned int* __restrict__ sgnh,
    float2* __restrict__ ppart)
{
    const int b  = blockIdx.x >> 6;
    const int jc = blockIdx.x & 63;
    const int i  = threadIdx.x;

    uint4 uu[8];
    #pragma unroll
    for (int q = 0; q < 8; ++q)
        uu[q] = *reinterpret_cast<const uint4*>(&uh[(size_t)(((b * 8 + q) << 9) + i) * 4]);

    unsigned int sgv[32];
    #pragma unroll
    for (int c = 0; c < 32; ++c)
        sgv[c] = __builtin_amdgcn_readfirstlane(sgnh[c]);

    float s = 0.f, sp = 0.f;
    #pragma unroll 1
    for (int rep = 0; rep < PROBE_REPS; ++rep) {
        const unsigned int* vhr = vh;
        const float2* epjr = epj;
        asm volatile("" : "+s"(vhr), "+s"(epjr));   // opaque: no cross-rep CSE
        k2_body(vhr, epjr, uu, sgv, b, jc * CHUNK, s, sp);
        asm volatile("" :: "v"(s), "v"(sp));        // keep each rep live
    }
    ppart[(size_t)(((b << 6) + jc) << 9) + i] = make_float2(s, sp);
}

// ---------------- Kernel 3: combine partials ----------------
__global__ __launch_bounds__(128) void k3_final(
    const float2* __restrict__ part, const float* __restrict__ cterm,
    float* __restrict__ out)
{
    const int t = blockIdx.x * 128 + threadIdx.x;   // 0..8191
    const int b = t >> 9, i = t & 511;
    float s = 0.f, sp = 0.f;
    #pragma unroll 8
    for (int jc = 0; jc < JCH; ++jc) {
        const float2 v = part[(size_t)(((b << 6) + jc) << 9) + i];
        s  += v.x;
        sp += v.y;
    }
    out[t] = sp / s + *cterm;
}

extern "C" void kernel_launch(void* const* d_in, const int* in_sizes, int n_in,
                              void* d_out, int out_size, void* d_ws, size_t ws_size,
                              hipStream_t stream) {
    const float* x    = (const float*)d_in[0];
    const float* Wl   = (const float*)d_in[1];
    const float* bl   = (const float*)d_in[2];
    const float* Wr   = (const float*)d_in[3];
    const float* br   = (const float*)d_in[4];
    const float* att  = (const float*)d_in[5];
    const float* bias = (const float*)d_in[6];
    const float* Wf   = (const float*)d_in[7];
    const float* bf   = (const float*)d_in[8];
    float* out = (float*)d_out;

    unsigned char* ws = (unsigned char*)d_ws;
    unsigned int* uh   = (unsigned int*)ws;                     // ROWS*32 u32 (1 MB)
    unsigned int* vh   = uh + (size_t)ROWS * 32;                // ROWS*32 u32 (1 MB)
    float2*       part = (float2*)(vh + (size_t)ROWS * 32);     // B*JCH*NN float2 (4 MB)
    float2*       ppart= part + (size_t)BB * JCH * NN;          // 4 MB probe scratch
    float2*       epj  = ppart + (size_t)BB * JCH * NN;         // ROWS float2 (64 KB)
    unsigned int* sgnh = (unsigned int*)(epj + ROWS);           // 32 u32
    float*        ctp  = (float*)(sgnh + 32);                   // 1 float

    k1_transform<<<ROWS / RB, 256, 0, stream>>>(x, Wl, bl, Wr, br, att, bias, Wf, bf,
                                                uh, vh, epj, sgnh, ctp);
    k2_attn<<<BB * JCH, 512, 0, stream>>>(uh, vh, epj, sgnh, part);
    k3_final<<<ROWS / 128, 128, 0, stream>>>(part, ctp, out);
    k2_probe<<<BB * JCH, 512, 0, stream>>>(uh, vh, epj, sgnh, ppart);
}

// Round 10
// 37.429 us; speedup vs baseline: 4.6057x; 4.6057x over previous
//
#include <hip/hip_runtime.h>
#include <hip/hip_fp16.h>

#define BB 16
#define NN 512
#define DD 64
#define ROWS (BB * NN)   // 8192
#define RB 32            // rows per k1 block
#define JCH 64           // j-chunks per sample in k2
#define CHUNK (NN / JCH) // 8 sources per chunk

typedef _Float16 v8h  __attribute__((ext_vector_type(8)));
typedef float    v4f  __attribute__((ext_vector_type(4)));
typedef unsigned int u32x16 __attribute__((ext_vector_type(16)));
typedef unsigned int u32x2v __attribute__((ext_vector_type(2)));

static __device__ __forceinline__ __half2 h2bits(unsigned int u) {
    union { unsigned int i; __half2 h; } c; c.i = u; return c.h;
}
static __device__ __forceinline__ unsigned int bits2(__half2 h) {
    union { __half2 h; unsigned int i; } c; c.h = h; return c.i;
}
// acc += sign2 * |u2 + v2|   (v_pk_add_f16, v_and_b32, v_pk_fma_f16)
static __device__ __forceinline__ __half2 absterm(unsigned int s, unsigned int u,
                                                  unsigned int v, __half2 a) {
    return __hfma2(h2bits(s), __habs2(__hadd2(h2bits(u), h2bits(v))), a);
}
static __device__ __forceinline__ v8h load_cvt8(const float* __restrict__ p) {
    const float4 a = *reinterpret_cast<const float4*>(p);
    const float4 b = *reinterpret_cast<const float4*>(p + 4);
    v8h r;
    r[0] = (_Float16)a.x; r[1] = (_Float16)a.y; r[2] = (_Float16)a.z; r[3] = (_Float16)a.w;
    r[4] = (_Float16)b.x; r[5] = (_Float16)b.y; r[6] = (_Float16)b.z; r[7] = (_Float16)b.w;
    return r;
}

// ---------------- Kernel 1: node transforms via MFMA ----------------
// uh: [b][q][i] packed half2 (per-lane coalesced reads in k2)
// vh: [b][j][32 u32] row-major 128B rows (scalar s_load rows in k2)
__global__ __launch_bounds__(256, 2) void k1_transform(
    const float* __restrict__ x,
    const float* __restrict__ Wl, const float* __restrict__ bl,
    const float* __restrict__ Wr, const float* __restrict__ br,
    const float* __restrict__ att, const float* __restrict__ bias,
    const float* __restrict__ Wf, const float* __restrict__ bf,
    unsigned int* __restrict__ uh, unsigned int* __restrict__ vh,
    float2* __restrict__ epj,
    unsigned int* __restrict__ sgnh, float* __restrict__ cterm)
{
    __shared__ float xacc[RB][132];
    __shared__ float red[RB][16][2];

    const int tid = threadIdx.x;
    const int r0 = blockIdx.x * RB;

    {
        const int w    = tid >> 6;
        const int lane = tid & 63;
        const int rowhalf = w >> 1;
        const int colhalf = w & 1;
        const int kb = (lane >> 4) * 8;

        const int arow = r0 + rowhalf * 16 + (lane & 15);
        const v8h A0 = load_cvt8(&x[(size_t)arow * DD + 0  + kb]);
        const v8h A1 = load_cvt8(&x[(size_t)arow * DD + 32 + kb]);

        v4f acc[4];
        #pragma unroll
        for (int t = 0; t < 4; ++t) acc[t] = (v4f){0.f, 0.f, 0.f, 0.f};

        #pragma unroll
        for (int t = 0; t < 4; ++t) {
            const int c = colhalf * 64 + t * 16 + (lane & 15);
            const float* wrow = (c < 64) ? (Wl + (size_t)c * DD)
                                         : (Wr + (size_t)(c - 64) * DD);
            const v8h B0 = load_cvt8(wrow + 0  + kb);
            const v8h B1 = load_cvt8(wrow + 32 + kb);
            acc[t] = __builtin_amdgcn_mfma_f32_16x16x32_f16(A0, B0, acc[t], 0, 0, 0);
            acc[t] = __builtin_amdgcn_mfma_f32_16x16x32_f16(A1, B1, acc[t], 0, 0, 0);
        }

        const int rbase = rowhalf * 16 + (lane >> 4) * 4;
        #pragma unroll
        for (int t = 0; t < 4; ++t) {
            const int col = colhalf * 64 + t * 16 + (lane & 15);
            #pragma unroll
            for (int r = 0; r < 4; ++r)
                xacc[rbase + r][col] = acc[t][r];
        }
    }
    __syncthreads();

    {
        const int g  = tid & 31;
        const int rq = tid >> 5;
        const int c0 = g * 4;
        const int ra = rq * 4;
        const bool isL = (c0 < 64);
        const int d0 = c0 & 63;

        const float4 bv = *reinterpret_cast<const float4*>((isL ? bl : br) + d0);
        const float4 av = *reinterpret_cast<const float4*>(&att[d0]);
        const float4 wfv = *reinterpret_cast<const float4*>(&Wf[d0]);

        const int q    = d0 >> 3;
        const int slot = (d0 & 4) ? 2 : 0;
        const int ubase = ((r0 >> 9) * 8 + q) * 512 + (r0 & 511);

        #pragma unroll
        for (int r = 0; r < 4; ++r) {
            float4 val = *reinterpret_cast<const float4*>(&xacc[ra + r][c0]);
            val.x += bv.x; val.y += bv.y; val.z += bv.z; val.w += bv.w;

            uint2 pk;
            pk.x = bits2(__floats2half2_rn(0.4f * av.x * val.x, 0.4f * av.y * val.y));
            pk.y = bits2(__floats2half2_rn(0.4f * av.z * val.z, 0.4f * av.w * val.w));

            if (isL) {
                red[ra + r][g][0] = av.x * val.x + av.y * val.y + av.z * val.z + av.w * val.w;
                red[ra + r][g][1] = wfv.x * val.x + wfv.y * val.y + wfv.z * val.z + wfv.w * val.w;
                // vh row-major: row = r0+ra+r, u32 offset d0/2
                *reinterpret_cast<uint2*>(&vh[(size_t)(r0 + ra + r) * 32 + (d0 >> 1)]) = pk;
            } else {
                *reinterpret_cast<uint2*>(&uh[(size_t)(ubase + ra + r) * 4 + slot]) = pk;
            }
        }
    }
    __syncthreads();

    if (tid < RB) {
        float a = 0.f, p = 0.f;
        #pragma unroll
        for (int gg = 0; gg < 16; ++gg) {
            a += red[tid][gg][0];
            p += red[tid][gg][1];
        }
        const float E = __expf(0.6f * a);
        epj[r0 + tid] = make_float2(E, E * p);
    }

    if (blockIdx.x == 0) {
        if (tid < 32) {
            const float s0 = (att[2 * tid]     >= 0.f) ? 1.f : -1.f;
            const float s1 = (att[2 * tid + 1] >= 0.f) ? 1.f : -1.f;
            sgnh[tid] = bits2(__floats2half2_rn(s0, s1));
        }
        if (tid == 0) {
            float ct = bf[0];
            #pragma unroll 8
            for (int d = 0; d < DD; ++d) ct = fmaf(bias[d], Wf[d], ct);
            *cterm = ct;
        }
    }
}

// ---------------- Kernel 2: streaming scores, scalar-pipe v loads ----------
// grid: B*JCH = 1024 blocks x 512; thread owns TARGET i (u-row in 32 VGPRs).
// Per source j: whole v-row via 2x s_load_dwordx16 + ep via s_load_dwordx2,
// double-buffered (issue before compute of other buffer). Inner loop pure VALU.
#define SCORE(X0, X1, EP)                                                   \
    {                                                                       \
        __half2 a0 = __float2half2_rn(0.f), a1 = a0, a2 = a0, a3 = a0;      \
        _Pragma("unroll")                                                   \
        for (int q = 0; q < 4; ++q) {                                       \
            a0 = absterm(sg[q].x, uu[q].x, X0[q * 4 + 0], a0);              \
            a1 = absterm(sg[q].y, uu[q].y, X0[q * 4 + 1], a1);              \
            a2 = absterm(sg[q].z, uu[q].z, X0[q * 4 + 2], a2);              \
            a3 = absterm(sg[q].w, uu[q].w, X0[q * 4 + 3], a3);              \
        }                                                                   \
        _Pragma("unroll")                                                   \
        for (int q = 0; q < 4; ++q) {                                       \
            a0 = absterm(sg[q + 4].x, uu[q + 4].x, X1[q * 4 + 0], a0);      \
            a1 = absterm(sg[q + 4].y, uu[q + 4].y, X1[q * 4 + 1], a1);      \
            a2 = absterm(sg[q + 4].z, uu[q + 4].z, X1[q * 4 + 2], a2);      \
            a3 = absterm(sg[q + 4].w, uu[q + 4].w, X1[q * 4 + 3], a3);      \
        }                                                                   \
        const __half2 hh = __hadd2(__hadd2(a0, a1), __hadd2(a2, a3));       \
        const float f = __low2float(hh) + __high2float(hh);                 \
        const float t = __expf(f);                                          \
        s  = fmaf(t, __uint_as_float(EP[0]), s);                            \
        sp = fmaf(t, __uint_as_float(EP[1]), sp);                           \
    }

__global__ __launch_bounds__(512, 6) void k2_attn(
    const unsigned int* __restrict__ uh, const unsigned int* __restrict__ vh,
    const float2* __restrict__ epj, const unsigned int* __restrict__ sgnh,
    float2* __restrict__ part)
{
    const int b  = blockIdx.x >> 6;
    const int jc = blockIdx.x & 63;
    const int i  = threadIdx.x;

    uint4 uu[8];
    #pragma unroll
    for (int q = 0; q < 8; ++q)
        uu[q] = *reinterpret_cast<const uint4*>(&uh[(size_t)(((b * 8 + q) << 9) + i) * 4]);

    uint4 sg[8];
    #pragma unroll
    for (int q = 0; q < 8; ++q)
        sg[q] = reinterpret_cast<const uint4*>(sgnh)[q];

    const int j0 = jc * CHUNK;
    const unsigned int* vrow = vh + (size_t)(b * NN + j0) * 32;   // 128B rows
    const float2* erow = epj + b * NN + j0;

    u32x16 A0, A1, B0, B1;
    u32x2v eA, eB;

    asm volatile("s_load_dwordx16 %0, %1, 0x0"  : "=s"(A0) : "s"(vrow));
    asm volatile("s_load_dwordx16 %0, %1, 0x40" : "=s"(A1) : "s"(vrow));
    asm volatile("s_load_dwordx2  %0, %1, 0x0"  : "=s"(eA) : "s"(erow));

    float s = 0.f, sp = 0.f;

    #pragma unroll
    for (int p = 0; p < CHUNK / 2; ++p) {
        // even j = 2p: wait A, prefetch odd j into B, compute A
        asm volatile("s_waitcnt lgkmcnt(0)" : "+s"(A0), "+s"(A1), "+s"(eA));
        {
            const unsigned int* vn = vrow + (2 * p + 1) * 32;
            const float2* en = erow + (2 * p + 1);
            asm volatile("s_load_dwordx16 %0, %1, 0x0"  : "=s"(B0) : "s"(vn));
            asm volatile("s_load_dwordx16 %0, %1, 0x40" : "=s"(B1) : "s"(vn));
            asm volatile("s_load_dwordx2  %0, %1, 0x0"  : "=s"(eB) : "s"(en));
        }
        SCORE(A0, A1, eA);

        // odd j = 2p+1: wait B, prefetch next even into A, compute B
        asm volatile("s_waitcnt lgkmcnt(0)" : "+s"(B0), "+s"(B1), "+s"(eB));
        if (p + 1 < CHUNK / 2) {
            const unsigned int* vn = vrow + (2 * p + 2) * 32;
            const float2* en = erow + (2 * p + 2);
            asm volatile("s_load_dwordx16 %0, %1, 0x0"  : "=s"(A0) : "s"(vn));
            asm volatile("s_load_dwordx16 %0, %1, 0x40" : "=s"(A1) : "s"(vn));
            asm volatile("s_load_dwordx2  %0, %1, 0x0"  : "=s"(eA) : "s"(en));
        }
        SCORE(B0, B1, eB);
    }

    part[(size_t)(((b << 6) + jc) << 9) + i] = make_float2(s, sp);
}

// ---------------- Kernel 3: combine partials ----------------
__global__ __launch_bounds__(128) void k3_final(
    const float2* __restrict__ part, const float* __restrict__ cterm,
    float* __restrict__ out)
{
    const int t = blockIdx.x * 128 + threadIdx.x;   // 0..8191
    const int b = t >> 9, i = t & 511;
    float s = 0.f, sp = 0.f;
    #pragma unroll 8
    for (int jc = 0; jc < JCH; ++jc) {
        const float2 v = part[(size_t)(((b << 6) + jc) << 9) + i];
        s  += v.x;
        sp += v.y;
    }
    out[t] = sp / s + *cterm;
}

extern "C" void kernel_launch(void* const* d_in, const int* in_sizes, int n_in,
                              void* d_out, int out_size, void* d_ws, size_t ws_size,
                              hipStream_t stream) {
    const float* x    = (const float*)d_in[0];
    const float* Wl   = (const float*)d_in[1];
    const float* bl   = (const float*)d_in[2];
    const float* Wr   = (const float*)d_in[3];
    const float* br   = (const float*)d_in[4];
    const float* att  = (const float*)d_in[5];
    const float* bias = (const float*)d_in[6];
    const float* Wf   = (const float*)d_in[7];
    const float* bf   = (const float*)d_in[8];
    float* out = (float*)d_out;

    unsigned char* ws = (unsigned char*)d_ws;
    unsigned int* uh   = (unsigned int*)ws;                     // ROWS*32 u32 (1 MB)
    unsigned int* vh   = uh + (size_t)ROWS * 32;                // ROWS*32 u32 (1 MB), 128B rows
    float2*       part = (float2*)(vh + (size_t)ROWS * 32);     // B*JCH*NN float2 (4 MB)
    float2*       epj  = part + (size_t)BB * JCH * NN;          // ROWS float2 (64 KB)
    unsigned int* sgnh = (unsigned int*)(epj + ROWS);           // 32 u32
    float*        ctp  = (float*)(sgnh + 32);                   // 1 float

    k1_transform<<<ROWS / RB, 256, 0, stream>>>(x, Wl, bl, Wr, br, att, bias, Wf, bf,
                                                uh, vh, epj, sgnh, ctp);
    k2_attn<<<BB * JCH, 512, 0, stream>>>(uh, vh, epj, sgnh, part);
    k3_final<<<ROWS / 128, 128, 0, stream>>>(part, ctp, out);
}

// Round 11
// 32.402 us; speedup vs baseline: 5.3202x; 1.1551x over previous
//
#include <hip/hip_runtime.h>
#include <hip/hip_fp16.h>

#define BB 16
#define NN 512
#define DD 64
#define ROWS (BB * NN)   // 8192
#define RB 32            // rows per k1 block
#define JCH 64           // j-chunks per sample in k2
#define CHUNK (NN / JCH) // 8 sources per chunk

typedef _Float16 v8h __attribute__((ext_vector_type(8)));
typedef float    v4f __attribute__((ext_vector_type(4)));

static __device__ __forceinline__ __half2 h2bits(unsigned int u) {
    union { unsigned int i; __half2 h; } c; c.i = u; return c.h;
}
static __device__ __forceinline__ unsigned int bits2(__half2 h) {
    union { __half2 h; unsigned int i; } c; c.h = h; return c.i;
}
// acc += sign2 * |u2 + v2|   (v_pk_add_f16, v_and_b32, v_pk_fma_f16)
static __device__ __forceinline__ __half2 absterm(unsigned int s, unsigned int u,
                                                  unsigned int v, __half2 a) {
    return __hfma2(h2bits(s), __habs2(__hadd2(h2bits(u), h2bits(v))), a);
}
static __device__ __forceinline__ v8h load_cvt8(const float* __restrict__ p) {
    const float4 a = *reinterpret_cast<const float4*>(p);
    const float4 b = *reinterpret_cast<const float4*>(p + 4);
    v8h r;
    r[0] = (_Float16)a.x; r[1] = (_Float16)a.y; r[2] = (_Float16)a.z; r[3] = (_Float16)a.w;
    r[4] = (_Float16)b.x; r[5] = (_Float16)b.y; r[6] = (_Float16)b.z; r[7] = (_Float16)b.w;
    return r;
}

// ---------------- Kernel 1: node transforms via MFMA (R8 structure) ----------
// uh/vh: [b][q][i] packed half2, chunk-major (per-lane coalesced, wave-uniform
// v reads in k2).
__global__ __launch_bounds__(256, 2) void k1_transform(
    const float* __restrict__ x,
    const float* __restrict__ Wl, const float* __restrict__ bl,
    const float* __restrict__ Wr, const float* __restrict__ br,
    const float* __restrict__ att, const float* __restrict__ bias,
    const float* __restrict__ Wf, const float* __restrict__ bf,
    unsigned int* __restrict__ uh, unsigned int* __restrict__ vh,
    float2* __restrict__ epj,
    unsigned int* __restrict__ sgnh, float* __restrict__ cterm)
{
    __shared__ float xacc[RB][132];
    __shared__ float red[RB][16][2];

    const int tid = threadIdx.x;
    const int r0 = blockIdx.x * RB;

    {
        const int w    = tid >> 6;
        const int lane = tid & 63;
        const int rowhalf = w >> 1;
        const int colhalf = w & 1;
        const int kb = (lane >> 4) * 8;

        const int arow = r0 + rowhalf * 16 + (lane & 15);
        const v8h A0 = load_cvt8(&x[(size_t)arow * DD + 0  + kb]);
        const v8h A1 = load_cvt8(&x[(size_t)arow * DD + 32 + kb]);

        v4f acc[4];
        #pragma unroll
        for (int t = 0; t < 4; ++t) acc[t] = (v4f){0.f, 0.f, 0.f, 0.f};

        #pragma unroll
        for (int t = 0; t < 4; ++t) {
            const int c = colhalf * 64 + t * 16 + (lane & 15);
            const float* wrow = (c < 64) ? (Wl + (size_t)c * DD)
                                         : (Wr + (size_t)(c - 64) * DD);
            const v8h B0 = load_cvt8(wrow + 0  + kb);
            const v8h B1 = load_cvt8(wrow + 32 + kb);
            acc[t] = __builtin_amdgcn_mfma_f32_16x16x32_f16(A0, B0, acc[t], 0, 0, 0);
            acc[t] = __builtin_amdgcn_mfma_f32_16x16x32_f16(A1, B1, acc[t], 0, 0, 0);
        }

        const int rbase = rowhalf * 16 + (lane >> 4) * 4;
        #pragma unroll
        for (int t = 0; t < 4; ++t) {
            const int col = colhalf * 64 + t * 16 + (lane & 15);
            #pragma unroll
            for (int r = 0; r < 4; ++r)
                xacc[rbase + r][col] = acc[t][r];
        }
    }
    __syncthreads();

    {
        const int g  = tid & 31;
        const int rq = tid >> 5;
        const int c0 = g * 4;
        const int ra = rq * 4;
        const bool isL = (c0 < 64);
        const int d0 = c0 & 63;

        const float4 bv = *reinterpret_cast<const float4*>((isL ? bl : br) + d0);
        const float4 av = *reinterpret_cast<const float4*>(&att[d0]);
        const float4 wfv = *reinterpret_cast<const float4*>(&Wf[d0]);

        unsigned int* const dst = isL ? vh : uh;
        const int q    = d0 >> 3;
        const int slot = (d0 & 4) ? 2 : 0;
        const int base = ((r0 >> 9) * 8 + q) * 512 + (r0 & 511);

        #pragma unroll
        for (int r = 0; r < 4; ++r) {
            float4 val = *reinterpret_cast<const float4*>(&xacc[ra + r][c0]);
            val.x += bv.x; val.y += bv.y; val.z += bv.z; val.w += bv.w;

            if (isL) {
                red[ra + r][g][0] = av.x * val.x + av.y * val.y + av.z * val.z + av.w * val.w;
                red[ra + r][g][1] = wfv.x * val.x + wfv.y * val.y + wfv.z * val.z + wfv.w * val.w;
            }
            uint2 pk;
            pk.x = bits2(__floats2half2_rn(0.4f * av.x * val.x, 0.4f * av.y * val.y));
            pk.y = bits2(__floats2half2_rn(0.4f * av.z * val.z, 0.4f * av.w * val.w));
            *reinterpret_cast<uint2*>(&dst[(size_t)(base + ra + r) * 4 + slot]) = pk;
        }
    }
    __syncthreads();

    if (tid < RB) {
        float a = 0.f, p = 0.f;
        #pragma unroll
        for (int gg = 0; gg < 16; ++gg) {
            a += red[tid][gg][0];
            p += red[tid][gg][1];
        }
        const float E = __expf(0.6f * a);
        epj[r0 + tid] = make_float2(E, E * p);
    }

    if (blockIdx.x == 0) {
        if (tid < 32) {
            const float s0 = (att[2 * tid]     >= 0.f) ? 1.f : -1.f;
            const float s1 = (att[2 * tid + 1] >= 0.f) ? 1.f : -1.f;
            sgnh[tid] = bits2(__floats2half2_rn(s0, s1));
        }
        if (tid == 0) {
            float ct = bf[0];
            #pragma unroll 8
            for (int d = 0; d < DD; ++d) ct = fmaf(bias[d], Wf[d], ct);
            *cterm = ct;
        }
    }
}

// ---------------- Kernel 2: streaming scores (R9 config, probe removed) ------
// grid: B*JCH = 1024 blocks x 512 thr; thread owns TARGET i (u-row in 32 VGPRs).
// VGPR<=64 via launch_bounds(512,8): 8 waves/SIMD available, sgn in SGPRs.
__global__ __launch_bounds__(512, 8) void k2_attn(
    const unsigned int* __restrict__ uh, const unsigned int* __restrict__ vh,
    const float2* __restrict__ epj, const unsigned int* __restrict__ sgnh,
    float2* __restrict__ part)
{
    const int b  = blockIdx.x >> 6;
    const int jc = blockIdx.x & 63;
    const int i  = threadIdx.x;

    uint4 uu[8];
    #pragma unroll
    for (int q = 0; q < 8; ++q)
        uu[q] = *reinterpret_cast<const uint4*>(&uh[(size_t)(((b * 8 + q) << 9) + i) * 4]);

    unsigned int sgv[32];     // force SGPR residency
    #pragma unroll
    for (int c = 0; c < 32; ++c)
        sgv[c] = __builtin_amdgcn_readfirstlane(sgnh[c]);

    float s = 0.f, sp = 0.f;
    const int j0 = jc * CHUNK;

    #pragma unroll 2
    for (int jj = 0; jj < CHUNK; ++jj) {
        const int j = j0 + jj;
        __half2 a0 = __float2half2_rn(0.f), a1 = a0;
        #pragma unroll
        for (int q = 0; q < 8; ++q) {
            const uint4 vq = *reinterpret_cast<const uint4*>(
                &vh[(size_t)(((b * 8 + q) << 9) + j) * 4]);   // wave-uniform
            a0 = absterm(sgv[q * 4 + 0], uu[q].x, vq.x, a0);
            a1 = absterm(sgv[q * 4 + 1], uu[q].y, vq.y, a1);
            a0 = absterm(sgv[q * 4 + 2], uu[q].z, vq.z, a0);
            a1 = absterm(sgv[q * 4 + 3], uu[q].w, vq.w, a1);
        }
        const __half2 h = __hadd2(a0, a1);
        const float f = __low2float(h) + __high2float(h);
        const float t = __expf(f);
        const float2 ep = epj[(b << 9) + j];                   // wave-uniform
        s  = fmaf(t, ep.x, s);
        sp = fmaf(t, ep.y, sp);
    }
    part[(size_t)(((b << 6) + jc) << 9) + i] = make_float2(s, sp);
}

// ---------------- Kernel 3: combine partials ----------------
__global__ __launch_bounds__(128) void k3_final(
    const float2* __restrict__ part, const float* __restrict__ cterm,
    float* __restrict__ out)
{
    const int t = blockIdx.x * 128 + threadIdx.x;   // 0..8191
    const int b = t >> 9, i = t & 511;
    float s = 0.f, sp = 0.f;
    #pragma unroll 8
    for (int jc = 0; jc < JCH; ++jc) {
        const float2 v = part[(size_t)(((b << 6) + jc) << 9) + i];
        s  += v.x;
        sp += v.y;
    }
    out[t] = sp / s + *cterm;
}

extern "C" void kernel_launch(void* const* d_in, const int* in_sizes, int n_in,
                              void* d_out, int out_size, void* d_ws, size_t ws_size,
                              hipStream_t stream) {
    const float* x    = (const float*)d_in[0];
    const float* Wl   = (const float*)d_in[1];
    const float* bl   = (const float*)d_in[2];
    const float* Wr   = (const float*)d_in[3];
    const float* br   = (const float*)d_in[4];
    const float* att  = (const float*)d_in[5];
    const float* bias = (const float*)d_in[6];
    const float* Wf   = (const float*)d_in[7];
    const float* bf   = (const float*)d_in[8];
    float* out = (float*)d_out;

    unsigned char* ws = (unsigned char*)d_ws;
    unsigned int* uh   = (unsigned int*)ws;                     // ROWS*32 u32 (1 MB)
    unsigned int* vh   = uh + (size_t)ROWS * 32;                // ROWS*32 u32 (1 MB)
    float2*       part = (float2*)(vh + (size_t)ROWS * 32);     // B*JCH*NN float2 (4 MB)
    float2*       epj  = part + (size_t)BB * JCH * NN;          // ROWS float2 (64 KB)
    unsigned int* sgnh = (unsigned int*)(epj + ROWS);           // 32 u32
    float*        ctp  = (float*)(sgnh + 32);                   // 1 float

    k1_transform<<<ROWS / RB, 256, 0, stream>>>(x, Wl, bl, Wr, br, att, bias, Wf, bf,
                                                uh, vh, epj, sgnh, ctp);
    k2_attn<<<BB * JCH, 512, 0, stream>>>(uh, vh, epj, sgnh, part);
    k3_final<<<ROWS / 128, 128, 0, stream>>>(part, ctp, out);
}